// Round 1
// baseline (172.330 us; speedup 1.0000x reference)
//
#include <hip/hip_runtime.h>

// EMA recurrence y_t = b*x_t + (1-b)*y_{t-1}, y_{-1}=0, over (B,T,U)=(32,4096,512).
// 3-pass chunked scan exploiting time-constant decay a = 1-b:
//   pass1: chunk-local scan finals S[b][k][u]        (reads x)
//   pass2: carry-in per chunk via E_k = a^L*E_{k-1}+S_k  (tiny)
//   pass3: re-scan chunks seeded with carry-in, write y  (reads x, writes y)

namespace {

constexpr int kB  = 32;
constexpr int kT  = 4096;
constexpr int kU  = 512;
constexpr int kC  = 64;          // chunks along T
constexpr int kL  = kT / kC;     // 64 timesteps per chunk
constexpr int kU4 = kU / 4;      // 128 float4 channel groups

__global__ __launch_bounds__(256) void ema_pass1(
    const float* __restrict__ x, const float* __restrict__ bc,
    float4* __restrict__ S) {
  int g  = blockIdx.x * 256 + threadIdx.x;   // [0, kB*kC*kU4)
  int u4 = g % kU4;
  int k  = (g / kU4) % kC;
  int b  = g / (kU4 * kC);
  float4 bb = reinterpret_cast<const float4*>(bc)[u4];
  float ax = 1.f - bb.x, ay = 1.f - bb.y, az = 1.f - bb.z, aw = 1.f - bb.w;
  float sx = 0.f, sy = 0.f, sz = 0.f, sw = 0.f;
  const float4* xp = reinterpret_cast<const float4*>(x)
                   + ((size_t)b * kT + (size_t)k * kL) * kU4 + u4;
  #pragma unroll 8
  for (int i = 0; i < kL; ++i) {
    float4 v = xp[(size_t)i * kU4];
    sx = fmaf(ax, sx, bb.x * v.x);
    sy = fmaf(ay, sy, bb.y * v.y);
    sz = fmaf(az, sz, bb.z * v.z);
    sw = fmaf(aw, sw, bb.w * v.w);
  }
  S[((size_t)b * kC + k) * kU4 + u4] = make_float4(sx, sy, sz, sw);
}

__global__ __launch_bounds__(256) void ema_pass2(
    const float4* __restrict__ S, const float* __restrict__ bc,
    float4* __restrict__ carry) {
  int g  = blockIdx.x * 256 + threadIdx.x;   // [0, kB*kU4)
  int u4 = g % kU4;
  int b  = g / kU4;
  float4 bb = reinterpret_cast<const float4*>(bc)[u4];
  float px = 1.f - bb.x, py = 1.f - bb.y, pz = 1.f - bb.z, pw = 1.f - bb.w;
  // a^L with L = 64 = 2^6 via repeated squaring
  #pragma unroll
  for (int j = 0; j < 6; ++j) { px *= px; py *= py; pz *= pz; pw *= pw; }
  float ex = 0.f, ey = 0.f, ez = 0.f, ew = 0.f;
  for (int k = 0; k < kC; ++k) {
    size_t idx = ((size_t)b * kC + k) * kU4 + u4;
    carry[idx] = make_float4(ex, ey, ez, ew);   // carry-IN for chunk k
    float4 s = S[idx];
    ex = fmaf(px, ex, s.x);
    ey = fmaf(py, ey, s.y);
    ez = fmaf(pz, ez, s.z);
    ew = fmaf(pw, ew, s.w);
  }
}

__global__ __launch_bounds__(256) void ema_pass3(
    const float* __restrict__ x, const float* __restrict__ bc,
    const float4* __restrict__ carry, float* __restrict__ out) {
  int g  = blockIdx.x * 256 + threadIdx.x;   // [0, kB*kC*kU4)
  int u4 = g % kU4;
  int k  = (g / kU4) % kC;
  int b  = g / (kU4 * kC);
  float4 bb = reinterpret_cast<const float4*>(bc)[u4];
  float ax = 1.f - bb.x, ay = 1.f - bb.y, az = 1.f - bb.z, aw = 1.f - bb.w;
  float4 c = carry[((size_t)b * kC + k) * kU4 + u4];
  float yx = c.x, yy = c.y, yz = c.z, yw = c.w;
  size_t off = ((size_t)b * kT + (size_t)k * kL) * kU4 + u4;
  const float4* xp = reinterpret_cast<const float4*>(x) + off;
  float4*       op = reinterpret_cast<float4*>(out) + off;
  #pragma unroll 8
  for (int i = 0; i < kL; ++i) {
    float4 v = xp[(size_t)i * kU4];
    yx = fmaf(ax, yx, bb.x * v.x);
    yy = fmaf(ay, yy, bb.y * v.y);
    yz = fmaf(az, yz, bb.z * v.z);
    yw = fmaf(aw, yw, bb.w * v.w);
    op[(size_t)i * kU4] = make_float4(yx, yy, yz, yw);
  }
}

// Fallback if d_ws is too small: fully sequential per (b,u4). Slow but correct.
__global__ __launch_bounds__(256) void ema_fallback(
    const float* __restrict__ x, const float* __restrict__ bc,
    float* __restrict__ out) {
  int g = blockIdx.x * 256 + threadIdx.x;
  if (g >= kB * kU4) return;
  int u4 = g % kU4;
  int b  = g / kU4;
  float4 bb = reinterpret_cast<const float4*>(bc)[u4];
  float ax = 1.f - bb.x, ay = 1.f - bb.y, az = 1.f - bb.z, aw = 1.f - bb.w;
  float yx = 0.f, yy = 0.f, yz = 0.f, yw = 0.f;
  size_t off = (size_t)b * kT * kU4 + u4;
  const float4* xp = reinterpret_cast<const float4*>(x) + off;
  float4*       op = reinterpret_cast<float4*>(out) + off;
  for (int t = 0; t < kT; ++t) {
    float4 v = xp[(size_t)t * kU4];
    yx = fmaf(ax, yx, bb.x * v.x);
    yy = fmaf(ay, yy, bb.y * v.y);
    yz = fmaf(az, yz, bb.z * v.z);
    yw = fmaf(aw, yw, bb.w * v.w);
    op[(size_t)t * kU4] = make_float4(yx, yy, yz, yw);
  }
}

}  // namespace

extern "C" void kernel_launch(void* const* d_in, const int* in_sizes, int n_in,
                              void* d_out, int out_size, void* d_ws, size_t ws_size,
                              hipStream_t stream) {
  const float* x  = (const float*)d_in[0];
  const float* bc = (const float*)d_in[1];
  float* out = (float*)d_out;

  const size_t S_elems = (size_t)kB * kC * kU4;          // float4 count
  const size_t need = 2ull * S_elems * sizeof(float4);   // S + carry = 16 MiB
  if (ws_size >= need) {
    float4* S     = (float4*)d_ws;
    float4* carry = S + S_elems;
    ema_pass1<<<(kB * kC * kU4) / 256, 256, 0, stream>>>(x, bc, S);
    ema_pass2<<<(kB * kU4) / 256, 256, 0, stream>>>(S, bc, carry);
    ema_pass3<<<(kB * kC * kU4) / 256, 256, 0, stream>>>(x, bc, carry, out);
  } else {
    ema_fallback<<<(kB * kU4 + 255) / 256, 256, 0, stream>>>(x, bc, out);
  }
}